// Round 7
// baseline (194.526 us; speedup 1.0000x reference)
//
#include <hip/hip_runtime.h>
#include <math.h>

#define BB 32
#define CC 256
#define CQ 32      // C/8
#define NN 1024    // H*W

typedef short bf16x8 __attribute__((ext_vector_type(8)));
typedef float f32x4  __attribute__((ext_vector_type(4)));
typedef unsigned short u16;

// fp32 -> bf16 RNE
__device__ __forceinline__ u16 f2bf(float f) {
    unsigned u = __float_as_uint(f);
    u = (u + 0x7FFFu + ((u >> 16) & 1u)) >> 16;
    return (u16)u;
}

// ---------------------------------------------------------------------------
// Kernel 0: pack fused W = [Wq(32); Wk(32); Wv(256)] into MFMA A-frag order:
// wfrag[((rt*8 + kc)*64 + lane)*8 + j] = W[rt*16 + (lane&15)][kc*32 + (lane>>4)*8 + j]
// ---------------------------------------------------------------------------
__global__ void wpack_kernel(const float* __restrict__ Wq,
                             const float* __restrict__ Wk,
                             const float* __restrict__ Wv,
                             u16* __restrict__ wfrag)
{
    const int o = blockIdx.x * 256 + threadIdx.x;     // 0 .. 81919
    const int j    = o & 7;
    const int lane = (o >> 3) & 63;
    const int kc   = (o >> 9) & 7;
    const int rt   = o >> 12;                         // 0..19
    const int row  = rt * 16 + (lane & 15);
    const int col  = kc * 32 + (lane >> 4) * 8 + j;
    const float v = (row < 32) ? Wq[row * 256 + col]
                  : (row < 64) ? Wk[(row - 32) * 256 + col]
                               : Wv[(row - 64) * 256 + col];
    wfrag[o] = f2bf(v);
}

// ---------------------------------------------------------------------------
// Kernel 1: QKV projection via MFMA. Grid 1024 1D, XCD-swizzled so batch b
// lands on XCD b>>2 (same decode as attn -> vv handoff stays in that L2).
// Per block: 32-n tile. qt,kt: [b][n][32 d] bf16 ; vv: [b][c][n] bf16.
// ---------------------------------------------------------------------------
struct QSmem {
    union {
        u16 xs[32][272];     // x^T tile [n][c] bf16 (17,408 B)
        u16 osv[CC][40];     // v result [c][n]     (20,480 B)
    };
    u16 osqk[32][72];        // q|k result [n][d], d 0..31 = q, 32..63 = k
};

__global__ __launch_bounds__(256, 4) void qkv_kernel(
    const float* __restrict__ x, const u16* __restrict__ wfrag,
    const float* __restrict__ bq, const float* __restrict__ bk,
    const float* __restrict__ bv,
    u16* __restrict__ qt, u16* __restrict__ kt, u16* __restrict__ vv)
{
    __shared__ QSmem sm;
    const int bid  = blockIdx.x;
    const int xcd  = bid & 7;
    const int slot = bid >> 3;                 // 0..127
    const int b    = (xcd << 2) | (slot >> 5); // 4 batches per XCD
    const int n0   = (slot & 31) * 32;

    const int t = threadIdx.x;
    const int lane = t & 63, w = t >> 6;
    const int quad = lane >> 4, c16 = lane & 15;

    // ---- stage x^T bf16: 8 coalesced float4 loads/thread, all in flight
    {
        const float* xb = x + (size_t)b * CC * NN + n0;
        const int cr = t >> 3;            // 0..31
        const int n4 = (t & 7) * 4;       // n quad
        float4 f[8];
#pragma unroll
        for (int it = 0; it < 8; ++it)
            f[it] = *(const float4*)(xb + (size_t)(cr + 32 * it) * NN + n4);
#pragma unroll
        for (int it = 0; it < 8; ++it) {
            const int c = cr + 32 * it;
            sm.xs[n4 + 0][c] = f2bf(f[it].x);
            sm.xs[n4 + 1][c] = f2bf(f[it].y);
            sm.xs[n4 + 2][c] = f2bf(f[it].z);
            sm.xs[n4 + 3][c] = f2bf(f[it].w);
        }
    }
    __syncthreads();

    f32x4 acc[5][2];
#pragma unroll
    for (int i = 0; i < 5; ++i)
#pragma unroll
        for (int j = 0; j < 2; ++j) acc[i][j] = (f32x4){0.f, 0.f, 0.f, 0.f};

#pragma unroll 2
    for (int k = 0; k < 8; ++k) {
        const int c0 = k * 32;
        bf16x8 wa[5], xb[2];
#pragma unroll
        for (int rs = 0; rs < 5; ++rs)   // swizzled W: 16 B/lane contiguous
            wa[rs] = *(const bf16x8*)&wfrag[(size_t)(((w * 5 + rs) * 8 + k) * 64 + lane) * 8];
#pragma unroll
        for (int ns = 0; ns < 2; ++ns)   // B: n-col = lane&15, k=c=quad*8+j
            xb[ns] = *(const bf16x8*)&sm.xs[ns * 16 + c16][c0 + quad * 8];
#pragma unroll
        for (int rs = 0; rs < 5; ++rs)
#pragma unroll
            for (int ns = 0; ns < 2; ++ns)
                acc[rs][ns] = __builtin_amdgcn_mfma_f32_16x16x32_bf16(
                    wa[rs], xb[ns], acc[rs][ns], 0, 0, 0);
    }

    __syncthreads();   // xs dead; osv may alias it now

    // ---- scatter D + bias into LDS result tiles (bf16)
#pragma unroll
    for (int rs = 0; rs < 5; ++rs) {
#pragma unroll
        for (int r = 0; r < 4; ++r) {
            const int rg = w * 80 + rs * 16 + quad * 4 + r;
            const float bias = (rg < 32) ? bq[rg] : (rg < 64) ? bk[rg - 32] : bv[rg - 64];
#pragma unroll
            for (int ns = 0; ns < 2; ++ns) {
                const int n = ns * 16 + c16;
                const u16 h = f2bf(acc[rs][ns][r] + bias);
                if (rg < 64) sm.osqk[n][rg] = h;
                else         sm.osv[rg - 64][n] = h;
            }
        }
    }
    __syncthreads();

    // ---- coalesced global writes
    // qt/kt: waves 0,1 -> qt ; waves 2,3 -> kt (each matrix 2 KB contiguous)
    {
        u16* dst = (w >= 2) ? kt : qt;
        const int dof = (w >= 2) ? 32 : 0;
        const size_t base = ((size_t)b * NN + n0) * CQ;
        const int o = (w & 1) * 512 + lane * 8;   // flat in [32 n][32 d]
        const int n = o >> 5, d = o & 31;
        const bf16x8 v = *(const bf16x8*)&sm.osqk[n][d + dof];
        *(bf16x8*)&dst[base + o] = v;
    }
    // vv: 4 stores/thread over [256 c][32 n]
#pragma unroll
    for (int it = 0; it < 4; ++it) {
        const int o = it * 2048 + t * 8;
        const int c = o >> 5, n = o & 31;
        const bf16x8 v = *(const bf16x8*)&sm.osv[c][n];
        *(bf16x8*)&vv[((size_t)b * CC + c) * NN + n0 + n] = v;
    }
}

// ---------------------------------------------------------------------------
// Kernel 2: flash attention via MFMA (O^T form), no-max softmax, ones-row l.
// Grid 1024 1D, XCD-swizzled. 32-m tiles, 128-n steps, 4 blocks/CU.
// Wave w: S for (m-half = w&1, n-half = w>>1); PV for c-strip w*64.
// ---------------------------------------------------------------------------
__global__ __launch_bounds__(256, 4) void attn_kernel(
    const u16* __restrict__ qt, const u16* __restrict__ kt,
    const u16* __restrict__ vv, const float* __restrict__ x,
    const float* __restrict__ gamma_p, float* __restrict__ out)
{
    __shared__ float ps[2][32][132];  // P dbuf [m][n-step] f32 (33,792 B)

    const int bid  = blockIdx.x;
    const int xcd  = bid & 7;
    const int slot = bid >> 3;                 // 0..127
    const int b    = (xcd << 2) | (slot >> 5); // 4 batches per XCD
    const int m0   = (slot & 31) * 32;

    const int t = threadIdx.x, lane = t & 63, w = t >> 6;
    const int quad = lane >> 4, c16 = lane & 15;
    const int mh = (w & 1) * 16;     // S: m-half
    const int nh = (w >> 1) * 64;    // S: n-half within 128-step

    // Q A-frag: Q[m=lane&15][d=quad*8+j]
    const bf16x8 qa = *(const bf16x8*)&qt[((size_t)b * NN + m0 + mh + c16) * CQ + quad * 8];

    bf16x8 ones;
#pragma unroll
    for (int j = 0; j < 8; ++j) ones[j] = (short)0x3F80;   // bf16 1.0

    f32x4 accO[4][2];                // [cs][ms] of O^T: row=c, col=m
    f32x4 lsum[2];
#pragma unroll
    for (int i = 0; i < 4; ++i)
#pragma unroll
        for (int j = 0; j < 2; ++j) accO[i][j] = (f32x4){0.f, 0.f, 0.f, 0.f};
    lsum[0] = (f32x4){0.f, 0.f, 0.f, 0.f};
    lsum[1] = (f32x4){0.f, 0.f, 0.f, 0.f};

    const u16* vbase = vv + (size_t)b * CC * NN;   // V[c][n]
    const u16* kbase = kt + (size_t)b * NN * CQ;   // K^T[n][d]

    // pre-issue K frags for step 0 (this wave's n-half)
    bf16x8 kb[4];
#pragma unroll
    for (int s = 0; s < 4; ++s)
        kb[s] = *(const bf16x8*)&kbase[(size_t)(nh + s * 16 + c16) * CQ + quad * 8];

    for (int step = 0; step < 8; ++step) {
        const int nbase = step * 128;
        float* psb = &ps[step & 1][0][0];

        // V A-frags, first kc-half (n = nbase .. +63)
        bf16x8 va[4][2];
#pragma unroll
        for (int cs = 0; cs < 4; ++cs)
#pragma unroll
            for (int kc = 0; kc < 2; ++kc)
                va[cs][kc] = *(const bf16x8*)&vbase[
                    (size_t)(w * 64 + cs * 16 + c16) * NN + nbase + kc * 32 + quad * 8];

        // ---- S = Q·K^T strip [16 m][64 n] ----
        f32x4 accS[4];
#pragma unroll
        for (int s = 0; s < 4; ++s)
            accS[s] = __builtin_amdgcn_mfma_f32_16x16x32_bf16(
                qa, kb[s], (f32x4){0.f, 0.f, 0.f, 0.f}, 0, 0, 0);

        // ---- P = exp(S), unnormalized (|S| <= ~35: safe in fp32) ----
#pragma unroll
        for (int r = 0; r < 4; ++r)
#pragma unroll
            for (int s = 0; s < 4; ++s)
                psb[(mh + quad * 4 + r) * 132 + nh + s * 16 + c16] = __expf(accS[s][r]);

        // prefetch K frags for next step
        if (step < 7) {
#pragma unroll
            for (int s = 0; s < 4; ++s)
                kb[s] = *(const bf16x8*)&kbase[(size_t)(nbase + 128 + nh + s * 16 + c16) * CQ + quad * 8];
        }

        __syncthreads();             // ps[cur] visible to all waves

        // ---- PV first kc-half: O^T += V^T·P^T ; l += 1·P^T ----
#pragma unroll
        for (int ms = 0; ms < 2; ++ms) {
            bf16x8 pb[2];
#pragma unroll
            for (int kc = 0; kc < 2; ++kc) {
                const f32x4 p0 = *(const f32x4*)&psb[(ms * 16 + c16) * 132 + kc * 32 + quad * 8];
                const f32x4 p1 = *(const f32x4*)&psb[(ms * 16 + c16) * 132 + kc * 32 + quad * 8 + 4];
                bf16x8 pk;
                pk[0] = (short)f2bf(p0[0]); pk[1] = (short)f2bf(p0[1]);
                pk[2] = (short)f2bf(p0[2]); pk[3] = (short)f2bf(p0[3]);
                pk[4] = (short)f2bf(p1[0]); pk[5] = (short)f2bf(p1[1]);
                pk[6] = (short)f2bf(p1[2]); pk[7] = (short)f2bf(p1[3]);
                pb[kc] = pk;
            }
            lsum[ms] = __builtin_amdgcn_mfma_f32_16x16x32_bf16(ones, pb[0], lsum[ms], 0, 0, 0);
            lsum[ms] = __builtin_amdgcn_mfma_f32_16x16x32_bf16(ones, pb[1], lsum[ms], 0, 0, 0);
#pragma unroll
            for (int cs = 0; cs < 4; ++cs)
#pragma unroll
                for (int kc = 0; kc < 2; ++kc)
                    accO[cs][ms] = __builtin_amdgcn_mfma_f32_16x16x32_bf16(
                        va[cs][kc], pb[kc], accO[cs][ms], 0, 0, 0);
        }

        // V A-frags, second kc-half (n = nbase+64 .. +127)
#pragma unroll
        for (int cs = 0; cs < 4; ++cs)
#pragma unroll
            for (int kc = 0; kc < 2; ++kc)
                va[cs][kc] = *(const bf16x8*)&vbase[
                    (size_t)(w * 64 + cs * 16 + c16) * NN + nbase + 64 + kc * 32 + quad * 8];

#pragma unroll
        for (int ms = 0; ms < 2; ++ms) {
            bf16x8 pb[2];
#pragma unroll
            for (int kc = 0; kc < 2; ++kc) {
                const f32x4 p0 = *(const f32x4*)&psb[(ms * 16 + c16) * 132 + 64 + kc * 32 + quad * 8];
                const f32x4 p1 = *(const f32x4*)&psb[(ms * 16 + c16) * 132 + 64 + kc * 32 + quad * 8 + 4];
                bf16x8 pk;
                pk[0] = (short)f2bf(p0[0]); pk[1] = (short)f2bf(p0[1]);
                pk[2] = (short)f2bf(p0[2]); pk[3] = (short)f2bf(p0[3]);
                pk[4] = (short)f2bf(p1[0]); pk[5] = (short)f2bf(p1[1]);
                pk[6] = (short)f2bf(p1[2]); pk[7] = (short)f2bf(p1[3]);
                pb[kc] = pk;
            }
            lsum[ms] = __builtin_amdgcn_mfma_f32_16x16x32_bf16(ones, pb[0], lsum[ms], 0, 0, 0);
            lsum[ms] = __builtin_amdgcn_mfma_f32_16x16x32_bf16(ones, pb[1], lsum[ms], 0, 0, 0);
#pragma unroll
            for (int cs = 0; cs < 4; ++cs)
#pragma unroll
                for (int kc = 0; kc < 2; ++kc)
                    accO[cs][ms] = __builtin_amdgcn_mfma_f32_16x16x32_bf16(
                        va[cs][kc], pb[kc], accO[cs][ms], 0, 0, 0);
        }
    }

    // ---- epilogue: out = gamma * O / l + x ----
    const float gamma = gamma_p[0];
#pragma unroll
    for (int ms = 0; ms < 2; ++ms) {
        const float inv = gamma / lsum[ms][0];
        const int m = m0 + ms * 16 + c16;
#pragma unroll
        for (int cs = 0; cs < 4; ++cs) {
            const int cbase = w * 64 + cs * 16 + quad * 4;
#pragma unroll
            for (int r = 0; r < 4; ++r) {
                const size_t idx = ((size_t)b * CC + cbase + r) * NN + m;
                out[idx] = accO[cs][ms][r] * inv + x[idx];
            }
        }
    }
}

// ---------------------------------------------------------------------------
extern "C" void kernel_launch(void* const* d_in, const int* in_sizes, int n_in,
                              void* d_out, int out_size, void* d_ws, size_t ws_size,
                              hipStream_t stream)
{
    const float* x  = (const float*)d_in[0];
    const float* Wq = (const float*)d_in[1];
    const float* bq = (const float*)d_in[2];
    const float* Wk = (const float*)d_in[3];
    const float* bk = (const float*)d_in[4];
    const float* Wv = (const float*)d_in[5];
    const float* bv = (const float*)d_in[6];
    const float* gm = (const float*)d_in[7];
    float* out = (float*)d_out;

    // workspace (bf16): qt 2MB | kt 2MB | vv 16MB | wfrag 160KB
    u16* qt    = (u16*)d_ws;
    u16* kt    = qt + (size_t)BB * NN * CQ;
    u16* vv    = kt + (size_t)BB * NN * CQ;
    u16* wfrag = vv + (size_t)BB * CC * NN;

    wpack_kernel<<<320, 256, 0, stream>>>(Wq, Wk, Wv, wfrag);
    qkv_kernel<<<1024, 256, 0, stream>>>(x, wfrag, bq, bk, bv, qt, kt, vv);
    attn_kernel<<<1024, 256, 0, stream>>>(qt, kt, vv, x, gm, out);
}